// Round 1
// baseline (4221.734 us; speedup 1.0000x reference)
//
#include <hip/hip_runtime.h>

#define D_IN   1024
#define D_SAE  16384
#define KTOP   32
#define NROWS  8192

// ---------------------------------------------------------------------------
// Kernel 1: z_pre = (x - b_pre) @ W_enc^T     fp32 vector GEMM
// Block tile 128(n) x 128(s), K-step 16, 256 threads, 8x8 accum per thread.
// ---------------------------------------------------------------------------
__global__ __launch_bounds__(256, 2) void encode_gemm(
    const float* __restrict__ x, const float* __restrict__ b_pre,
    const float* __restrict__ W_enc, float* __restrict__ z_pre)
{
    __shared__ float As[16][132];   // [k][n], padded stride 132 (16B-aligned rows)
    __shared__ float Bs[16][132];   // [k][s]

    const int tid = threadIdx.x;
    const int n0  = blockIdx.y * 128;
    const int s0  = blockIdx.x * 128;
    const int ty  = tid >> 4;       // 0..15 -> 8 rows each
    const int tx  = tid & 15;       // 0..15 -> 8 cols each

    // staging: 512 float4 per tile; thread t handles float4 #t and #(t+256)
    const int r0  = tid >> 2;           // 0..63
    const int r1  = r0 + 64;            // 64..127
    const int kq  = (tid & 3) * 4;      // k offset 0,4,8,12

    float acc[8][8];
#pragma unroll
    for (int i = 0; i < 8; ++i)
#pragma unroll
        for (int j = 0; j < 8; ++j) acc[i][j] = 0.0f;

    const float* xA = x     + (size_t)n0 * D_IN;
    const float* wB = W_enc + (size_t)s0 * D_IN;

    for (int k0 = 0; k0 < D_IN; k0 += 16) {
        float4 a0 = *(const float4*)(xA + (size_t)r0 * D_IN + k0 + kq);
        float4 a1 = *(const float4*)(xA + (size_t)r1 * D_IN + k0 + kq);
        float4 b0 = *(const float4*)(wB + (size_t)r0 * D_IN + k0 + kq);
        float4 b1 = *(const float4*)(wB + (size_t)r1 * D_IN + k0 + kq);
        float4 bp = *(const float4*)(b_pre + k0 + kq);
        a0.x -= bp.x; a0.y -= bp.y; a0.z -= bp.z; a0.w -= bp.w;
        a1.x -= bp.x; a1.y -= bp.y; a1.z -= bp.z; a1.w -= bp.w;

        __syncthreads();   // previous compute done reading LDS
        As[kq + 0][r0] = a0.x; As[kq + 1][r0] = a0.y; As[kq + 2][r0] = a0.z; As[kq + 3][r0] = a0.w;
        As[kq + 0][r1] = a1.x; As[kq + 1][r1] = a1.y; As[kq + 2][r1] = a1.z; As[kq + 3][r1] = a1.w;
        Bs[kq + 0][r0] = b0.x; Bs[kq + 1][r0] = b0.y; Bs[kq + 2][r0] = b0.z; Bs[kq + 3][r0] = b0.w;
        Bs[kq + 0][r1] = b1.x; Bs[kq + 1][r1] = b1.y; Bs[kq + 2][r1] = b1.z; Bs[kq + 3][r1] = b1.w;
        __syncthreads();

#pragma unroll
        for (int kk = 0; kk < 16; ++kk) {
            float4 av0 = *(const float4*)&As[kk][ty * 8];
            float4 av1 = *(const float4*)&As[kk][ty * 8 + 4];
            float4 bv0 = *(const float4*)&Bs[kk][tx * 8];
            float4 bv1 = *(const float4*)&Bs[kk][tx * 8 + 4];
            float a[8] = {av0.x, av0.y, av0.z, av0.w, av1.x, av1.y, av1.z, av1.w};
            float b[8] = {bv0.x, bv0.y, bv0.z, bv0.w, bv1.x, bv1.y, bv1.z, bv1.w};
#pragma unroll
            for (int i = 0; i < 8; ++i)
#pragma unroll
                for (int j = 0; j < 8; ++j)
                    acc[i][j] = fmaf(a[i], b[j], acc[i][j]);
        }
    }

#pragma unroll
    for (int i = 0; i < 8; ++i) {
        float* dst = z_pre + (size_t)(n0 + ty * 8 + i) * D_SAE + s0 + tx * 8;
        *(float4*)(dst)     = make_float4(acc[i][0], acc[i][1], acc[i][2], acc[i][3]);
        *(float4*)(dst + 4) = make_float4(acc[i][4], acc[i][5], acc[i][6], acc[i][7]);
    }
}

// ---------------------------------------------------------------------------
// Kernel 2: exact per-row top-K via 4-level radix select on sortable uints.
// One block (256 thr) per row; row staged in LDS (64 KB). Ties -> lowest index
// (matches lax.top_k). Writes dense z and a compact (idx,val) list (sorted by
// idx for deterministic decode summation).
// ---------------------------------------------------------------------------
__global__ __launch_bounds__(256) void topk_select(
    const float* __restrict__ z_pre, float* __restrict__ z,
    int* __restrict__ out_idx, float* __restrict__ out_val)
{
    __shared__ unsigned int su[D_SAE];
    __shared__ unsigned int hist[256];
    __shared__ unsigned int sscan[256];
    __shared__ int s_bin; __shared__ unsigned int s_sub;
    __shared__ unsigned int eq_cnt, sel_cnt;
    __shared__ int eidx[64];
    __shared__ int s_need;
    __shared__ int cidx[KTOP];
    __shared__ float cval[KTOP];

    const int row = blockIdx.x;
    const int tid = threadIdx.x;
    const float* src = z_pre + (size_t)row * D_SAE;

    for (int i = tid; i < D_SAE; i += 256) {
        unsigned int b = __float_as_uint(src[i]);
        su[i] = (b & 0x80000000u) ? ~b : (b | 0x80000000u);
    }
    __syncthreads();

    unsigned int prefix = 0u, pmask = 0u;
    int need = KTOP;
    for (int level = 0; level < 4; ++level) {
        const int shift = 24 - 8 * level;
        hist[tid] = 0u;
        __syncthreads();
        for (int i = tid; i < D_SAE; i += 256) {
            unsigned int ui = su[i];
            if ((ui & pmask) == prefix)
                atomicAdd(&hist[(ui >> shift) & 0xffu], 1u);
        }
        __syncthreads();
        sscan[tid] = hist[tid];
        __syncthreads();
        for (int off = 1; off < 256; off <<= 1) {
            unsigned int v = (tid + off < 256) ? sscan[tid + off] : 0u;
            __syncthreads();
            sscan[tid] += v;
            __syncthreads();
        }
        // sscan[b] = #elems (in prefix class) with byte >= b  (non-increasing)
        {
            unsigned int ge = sscan[tid];
            unsigned int gt = (tid < 255) ? sscan[tid + 1] : 0u;
            if ((int)ge >= need && (int)gt < need) { s_bin = tid; s_sub = gt; }
        }
        __syncthreads();
        prefix |= ((unsigned int)s_bin) << shift;
        pmask  |= 0xffu << shift;
        need   -= (int)s_sub;
        __syncthreads();
    }
    const unsigned int T = prefix;   // mapped value of the K-th largest element

    if (tid == 0) { eq_cnt = 0u; sel_cnt = 0u; }
    __syncthreads();
    for (int i = tid; i < D_SAE; i += 256) {
        if (su[i] == T) {
            unsigned int p = atomicAdd(&eq_cnt, 1u);
            if (p < 64u) eidx[p] = i;
        }
    }
    __syncthreads();
    if (tid == 0) {
        int ec = (int)(eq_cnt < 64u ? eq_cnt : 64u);
        for (int a = 1; a < ec; ++a) {             // sort ascending by index
            int v = eidx[a]; int b = a - 1;
            while (b >= 0 && eidx[b] > v) { eidx[b + 1] = eidx[b]; --b; }
            eidx[b + 1] = v;
        }
        s_need = need;   // how many ties to keep (lowest indices)
    }
    __syncthreads();
    const int neq = s_need;

    for (int i = tid; i < D_SAE; i += 256) {
        unsigned int ui = su[i];
        bool sel = (ui > T);
        if (!sel && ui == T) {
            for (int k = 0; k < neq; ++k)
                if (eidx[k] == i) { sel = true; break; }
        }
        unsigned int fb = (ui & 0x80000000u) ? (ui & 0x7fffffffu) : ~ui;
        float fv = __uint_as_float(fb);
        z[(size_t)row * D_SAE + i] = sel ? fv : 0.0f;
        if (sel) {
            unsigned int p = atomicAdd(&sel_cnt, 1u);
            if (p < (unsigned)KTOP) { cidx[p] = i; cval[p] = fv; }
        }
    }
    __syncthreads();
    if (out_idx != nullptr) {
        if (tid == 0) {
            int m = (int)(sel_cnt < (unsigned)KTOP ? sel_cnt : (unsigned)KTOP);
            for (int a = 1; a < m; ++a) {          // sort pairs by index
                int vi = cidx[a]; float vv = cval[a]; int b = a - 1;
                while (b >= 0 && cidx[b] > vi) {
                    cidx[b + 1] = cidx[b]; cval[b + 1] = cval[b]; --b;
                }
                cidx[b + 1] = vi; cval[b + 1] = vv;
            }
            for (int a = m; a < KTOP; ++a) { cidx[a] = 0; cval[a] = 0.0f; }
        }
        __syncthreads();
        if (tid < KTOP) {
            out_idx[row * KTOP + tid] = cidx[tid];
            out_val[row * KTOP + tid] = cval[tid];
        }
    }
}

// ---------------------------------------------------------------------------
// Kernel 3: W_dec [D_IN][D_SAE] -> W_dec_T [D_SAE][D_IN]  (tiled transpose)
// ---------------------------------------------------------------------------
__global__ __launch_bounds__(256) void transpose_wdec(
    const float* __restrict__ in, float* __restrict__ out)
{
    __shared__ float tile[32][33];
    const int tid = threadIdx.x;
    const int lx = tid & 31, ly = tid >> 5;     // 32 x 8
    const int j0 = blockIdx.x * 32;             // along D_SAE
    const int d0 = blockIdx.y * 32;             // along D_IN
#pragma unroll
    for (int r = 0; r < 4; ++r) {
        int d = d0 + ly + r * 8;
        tile[ly + r * 8][lx] = in[(size_t)d * D_SAE + j0 + lx];
    }
    __syncthreads();
#pragma unroll
    for (int r = 0; r < 4; ++r) {
        int j = j0 + ly + r * 8;
        out[(size_t)j * D_IN + d0 + lx] = tile[lx][ly + r * 8];
    }
}

// ---------------------------------------------------------------------------
// Kernel 4a: x_hat[row,:] = sum_j val * W_dec_T[idx,:] + b_dec + b_pre (fast)
// ---------------------------------------------------------------------------
__global__ __launch_bounds__(256) void decode_fast(
    const float* __restrict__ WdT, const int* __restrict__ idx,
    const float* __restrict__ val, const float* __restrict__ b_pre,
    const float* __restrict__ b_dec, float* __restrict__ x_hat)
{
    __shared__ int   sj[KTOP];
    __shared__ float sv[KTOP];
    const int row = blockIdx.x, tid = threadIdx.x;
    if (tid < KTOP) { sj[tid] = idx[row * KTOP + tid]; sv[tid] = val[row * KTOP + tid]; }
    __syncthreads();
    const int d = tid * 4;
    float4 bd = *(const float4*)(b_dec + d);
    float4 bp = *(const float4*)(b_pre + d);
    float4 acc = make_float4(bd.x + bp.x, bd.y + bp.y, bd.z + bp.z, bd.w + bp.w);
#pragma unroll
    for (int j = 0; j < KTOP; ++j) {
        const float v = sv[j];
        const float4 w = *(const float4*)(WdT + (size_t)sj[j] * D_IN + d);
        acc.x = fmaf(v, w.x, acc.x); acc.y = fmaf(v, w.y, acc.y);
        acc.z = fmaf(v, w.z, acc.z); acc.w = fmaf(v, w.w, acc.w);
    }
    *(float4*)(x_hat + (size_t)row * D_IN + d) = acc;
}

// ---------------------------------------------------------------------------
// Kernel 4b: fallback decode without workspace (scans z, strided W_dec cols)
// ---------------------------------------------------------------------------
__global__ __launch_bounds__(256) void decode_slow(
    const float* __restrict__ W_dec, const float* __restrict__ z,
    const float* __restrict__ b_pre, const float* __restrict__ b_dec,
    float* __restrict__ x_hat)
{
    __shared__ int   sj[64];
    __shared__ float sv[64];
    __shared__ unsigned int cnt;
    __shared__ int s_m;
    const int row = blockIdx.x, tid = threadIdx.x;
    if (tid == 0) cnt = 0u;
    __syncthreads();
    const float* zr = z + (size_t)row * D_SAE;
    for (int i = tid; i < D_SAE; i += 256) {
        float v = zr[i];
        if (v != 0.0f) { unsigned p = atomicAdd(&cnt, 1u); if (p < 64u) { sj[p] = i; sv[p] = v; } }
    }
    __syncthreads();
    if (tid == 0) {
        int m = (int)(cnt < 64u ? cnt : 64u);
        for (int a = 1; a < m; ++a) {
            int vi = sj[a]; float vv = sv[a]; int b = a - 1;
            while (b >= 0 && sj[b] > vi) { sj[b + 1] = sj[b]; sv[b + 1] = sv[b]; --b; }
            sj[b + 1] = vi; sv[b + 1] = vv;
        }
        s_m = m;
    }
    __syncthreads();
    const int m = s_m;
    const int d = tid * 4;
    float4 bd = *(const float4*)(b_dec + d);
    float4 bp = *(const float4*)(b_pre + d);
    float4 acc = make_float4(bd.x + bp.x, bd.y + bp.y, bd.z + bp.z, bd.w + bp.w);
    for (int j = 0; j < m; ++j) {
        float v = sv[j];
        size_t c = (size_t)sj[j];
        acc.x = fmaf(v, W_dec[(size_t)(d + 0) * D_SAE + c], acc.x);
        acc.y = fmaf(v, W_dec[(size_t)(d + 1) * D_SAE + c], acc.y);
        acc.z = fmaf(v, W_dec[(size_t)(d + 2) * D_SAE + c], acc.z);
        acc.w = fmaf(v, W_dec[(size_t)(d + 3) * D_SAE + c], acc.w);
    }
    *(float4*)(x_hat + (size_t)row * D_IN + d) = acc;
}

// ---------------------------------------------------------------------------
extern "C" void kernel_launch(void* const* d_in, const int* in_sizes, int n_in,
                              void* d_out, int out_size, void* d_ws, size_t ws_size,
                              hipStream_t stream)
{
    const float* x     = (const float*)d_in[0];
    const float* b_pre = (const float*)d_in[1];
    const float* W_enc = (const float*)d_in[2];
    const float* W_dec = (const float*)d_in[3];
    const float* b_dec = (const float*)d_in[4];

    float* x_hat = (float*)d_out;
    float* z     = x_hat + (size_t)NROWS * D_IN;
    float* z_pre = z + (size_t)NROWS * D_SAE;

    const size_t wdt_bytes  = (size_t)D_SAE * D_IN * sizeof(float);
    const size_t list_bytes = (size_t)NROWS * KTOP * (sizeof(int) + sizeof(float));
    const bool fast = (ws_size >= wdt_bytes + list_bytes);

    float* WdT  = (float*)d_ws;
    int*   idxl = (int*)((char*)d_ws + wdt_bytes);
    float* vall = (float*)(idxl + (size_t)NROWS * KTOP);

    encode_gemm<<<dim3(D_SAE / 128, NROWS / 128), 256, 0, stream>>>(x, b_pre, W_enc, z_pre);

    if (fast) {
        transpose_wdec<<<dim3(D_SAE / 32, D_IN / 32), 256, 0, stream>>>(W_dec, WdT);
        topk_select<<<NROWS, 256, 0, stream>>>(z_pre, z, idxl, vall);
        decode_fast<<<NROWS, 256, 0, stream>>>(WdT, idxl, vall, b_pre, b_dec, x_hat);
    } else {
        topk_select<<<NROWS, 256, 0, stream>>>(z_pre, z, nullptr, nullptr);
        decode_slow<<<NROWS, 256, 0, stream>>>(W_dec, z, b_pre, b_dec, x_hat);
    }
}

// Round 3
// 1998.014 us; speedup vs baseline: 2.1130x; 2.1130x over previous
//
#include <hip/hip_runtime.h>

#define D_IN   1024
#define D_SAE  16384
#define KTOP   32
#define NROWS  8192
#define KSPLIT 3072   // A: [lo*2048 | hi | hi],  B: [hi | lo*2048 | hi]
#define LOSCALE 2048.0f
#define INV_LOSCALE 4.8828125e-4f   // 2^-11, exact

typedef _Float16 f16x8 __attribute__((ext_vector_type(8)));
typedef float    f32x4 __attribute__((ext_vector_type(4)));

// ---------------------------------------------------------------------------
// Split kernels: fp32 -> (hi, lo*2048) fp16 pair. Scaling keeps lo parts in
// the fp16 NORMAL range (w_lo ~1e-5 is subnormal and dies in the MFMA path).
// A2[n]: [0:1024)=lo(x0)*2048, [1024:2048)=hi(x0), [2048:3072)=hi(x0)
// B2[s]: [0:1024)=hi(w),       [1024:2048)=lo(w)*2048, [2048:3072)=hi(w)
// => k<2048 accumulates cross terms at 2^11 scale; then acc *= 2^-11;
//    k>=2048 accumulates hi*hi at full scale.
// ---------------------------------------------------------------------------
__global__ __launch_bounds__(256) void split_x(
    const float* __restrict__ x, const float* __restrict__ b_pre,
    _Float16* __restrict__ A2)
{
    const int n   = blockIdx.x;
    const int tid = threadIdx.x;
    const int k   = tid * 4;
    float4 v  = *(const float4*)(x + (size_t)n * D_IN + k);
    float4 bp = *(const float4*)(b_pre + k);
    v.x -= bp.x; v.y -= bp.y; v.z -= bp.z; v.w -= bp.w;
    _Float16 h[4], l[4];
    h[0] = (_Float16)v.x; l[0] = (_Float16)((v.x - (float)h[0]) * LOSCALE);
    h[1] = (_Float16)v.y; l[1] = (_Float16)((v.y - (float)h[1]) * LOSCALE);
    h[2] = (_Float16)v.z; l[2] = (_Float16)((v.z - (float)h[2]) * LOSCALE);
    h[3] = (_Float16)v.w; l[3] = (_Float16)((v.w - (float)h[3]) * LOSCALE);
    _Float16* row = A2 + (size_t)n * KSPLIT;
    *(ulong1*)(row + k)        = *(ulong1*)l;
    *(ulong1*)(row + 1024 + k) = *(ulong1*)h;
    *(ulong1*)(row + 2048 + k) = *(ulong1*)h;
}

__global__ __launch_bounds__(256) void split_w(
    const float* __restrict__ W_enc, _Float16* __restrict__ B2)
{
    const int s   = blockIdx.x;
    const int tid = threadIdx.x;
    const int k   = tid * 4;
    float4 v = *(const float4*)(W_enc + (size_t)s * D_IN + k);
    _Float16 h[4], l[4];
    h[0] = (_Float16)v.x; l[0] = (_Float16)((v.x - (float)h[0]) * LOSCALE);
    h[1] = (_Float16)v.y; l[1] = (_Float16)((v.y - (float)h[1]) * LOSCALE);
    h[2] = (_Float16)v.z; l[2] = (_Float16)((v.z - (float)h[2]) * LOSCALE);
    h[3] = (_Float16)v.w; l[3] = (_Float16)((v.w - (float)h[3]) * LOSCALE);
    _Float16* row = B2 + (size_t)s * KSPLIT;
    *(ulong1*)(row + k)        = *(ulong1*)h;
    *(ulong1*)(row + 1024 + k) = *(ulong1*)l;
    *(ulong1*)(row + 2048 + k) = *(ulong1*)h;
}

// ---------------------------------------------------------------------------
// Kernel 1: z_pre = A2 @ B2^T via mfma_f32_16x16x32_f16, K=3072,
// with one accumulator rescale (x 2^-11) at the k=2048 segment boundary.
// ---------------------------------------------------------------------------
__device__ __forceinline__ void gload_lds16(const void* g, void* lds) {
    __builtin_amdgcn_global_load_lds(
        (const __attribute__((address_space(1))) unsigned int*)g,
        (__attribute__((address_space(3))) unsigned int*)lds, 16, 0, 0);
}

__global__ __launch_bounds__(256, 2) void encode_mfma(
    const _Float16* __restrict__ A2, const _Float16* __restrict__ B2,
    float* __restrict__ z_pre)
{
    __shared__ _Float16 Asl[128 * 64];   // [row][k] row-major, 16 KB
    __shared__ _Float16 Bsl[128 * 64];

    const int tid  = threadIdx.x;
    const int wid  = tid >> 6;
    const int lane = tid & 63;
    const int wr   = wid >> 1;
    const int wc   = wid & 1;
    const int brow = blockIdx.y * 128;
    const int bcol = blockIdx.x * 128;

    const int srow = (lane >> 3);
    const int scol = (lane & 7) * 8;

    const int fr = lane & 15;
    const int fk = (lane >> 4) * 8;

    f32x4 acc[4][4] = {};

    for (int k0 = 0; k0 < KSPLIT; k0 += 64) {
        if (k0 == 2048) {      // cross-term segments done -> undo 2^11 scale
#pragma unroll
            for (int m = 0; m < 4; ++m)
#pragma unroll
                for (int n = 0; n < 4; ++n) {
                    acc[m][n][0] *= INV_LOSCALE;
                    acc[m][n][1] *= INV_LOSCALE;
                    acc[m][n][2] *= INV_LOSCALE;
                    acc[m][n][3] *= INV_LOSCALE;
                }
        }
#pragma unroll
        for (int t = 0; t < 4; ++t) {
            const int rg = (wid * 4 + t) * 8 + srow;
            const char* ldsA = (const char*)Asl + (wid * 4 + t) * 1024;
            const char* ldsB = (const char*)Bsl + (wid * 4 + t) * 1024;
            gload_lds16(A2 + (size_t)(brow + rg) * KSPLIT + k0 + scol, (void*)ldsA);
            gload_lds16(B2 + (size_t)(bcol + rg) * KSPLIT + k0 + scol, (void*)ldsB);
        }
        __syncthreads();

#pragma unroll
        for (int kk = 0; kk < 2; ++kk) {
            f16x8 a[4], b[4];
#pragma unroll
            for (int m = 0; m < 4; ++m)
                a[m] = *(const f16x8*)&Asl[(wr * 64 + m * 16 + fr) * 64 + kk * 32 + fk];
#pragma unroll
            for (int n = 0; n < 4; ++n)
                b[n] = *(const f16x8*)&Bsl[(wc * 64 + n * 16 + fr) * 64 + kk * 32 + fk];
#pragma unroll
            for (int m = 0; m < 4; ++m)
#pragma unroll
                for (int n = 0; n < 4; ++n)
                    acc[m][n] = __builtin_amdgcn_mfma_f32_16x16x32_f16(a[m], b[n], acc[m][n], 0, 0, 0);
        }
        __syncthreads();
    }

    // C/D layout: col = lane&15, row = (lane>>4)*4 + j   [m89 verified]
#pragma unroll
    for (int m = 0; m < 4; ++m) {
        const int r0 = brow + wr * 64 + m * 16 + (lane >> 4) * 4;
#pragma unroll
        for (int n = 0; n < 4; ++n) {
            float* dst = z_pre + (size_t)r0 * D_SAE + bcol + wc * 64 + n * 16 + (lane & 15);
#pragma unroll
            for (int j = 0; j < 4; ++j)
                dst[(size_t)j * D_SAE] = acc[m][n][j];
        }
    }
}

// ---------------------------------------------------------------------------
// Kernel 1 (fallback): fp32 vector GEMM (unchanged from R1)
// ---------------------------------------------------------------------------
__global__ __launch_bounds__(256, 2) void encode_gemm(
    const float* __restrict__ x, const float* __restrict__ b_pre,
    const float* __restrict__ W_enc, float* __restrict__ z_pre)
{
    __shared__ float As[16][132];
    __shared__ float Bs[16][132];
    const int tid = threadIdx.x;
    const int n0  = blockIdx.y * 128;
    const int s0  = blockIdx.x * 128;
    const int ty  = tid >> 4;
    const int tx  = tid & 15;
    const int r0  = tid >> 2;
    const int r1  = r0 + 64;
    const int kq  = (tid & 3) * 4;
    float acc[8][8];
#pragma unroll
    for (int i = 0; i < 8; ++i)
#pragma unroll
        for (int j = 0; j < 8; ++j) acc[i][j] = 0.0f;
    const float* xA = x     + (size_t)n0 * D_IN;
    const float* wB = W_enc + (size_t)s0 * D_IN;
    for (int k0 = 0; k0 < D_IN; k0 += 16) {
        float4 a0 = *(const float4*)(xA + (size_t)r0 * D_IN + k0 + kq);
        float4 a1 = *(const float4*)(xA + (size_t)r1 * D_IN + k0 + kq);
        float4 b0 = *(const float4*)(wB + (size_t)r0 * D_IN + k0 + kq);
        float4 b1 = *(const float4*)(wB + (size_t)r1 * D_IN + k0 + kq);
        float4 bp = *(const float4*)(b_pre + k0 + kq);
        a0.x -= bp.x; a0.y -= bp.y; a0.z -= bp.z; a0.w -= bp.w;
        a1.x -= bp.x; a1.y -= bp.y; a1.z -= bp.z; a1.w -= bp.w;
        __syncthreads();
        As[kq + 0][r0] = a0.x; As[kq + 1][r0] = a0.y; As[kq + 2][r0] = a0.z; As[kq + 3][r0] = a0.w;
        As[kq + 0][r1] = a1.x; As[kq + 1][r1] = a1.y; As[kq + 2][r1] = a1.z; As[kq + 3][r1] = a1.w;
        Bs[kq + 0][r0] = b0.x; Bs[kq + 1][r0] = b0.y; Bs[kq + 2][r0] = b0.z; Bs[kq + 3][r0] = b0.w;
        Bs[kq + 0][r1] = b1.x; Bs[kq + 1][r1] = b1.y; Bs[kq + 2][r1] = b1.z; Bs[kq + 3][r1] = b1.w;
        __syncthreads();
#pragma unroll
        for (int kk = 0; kk < 16; ++kk) {
            float4 av0 = *(const float4*)&As[kk][ty * 8];
            float4 av1 = *(const float4*)&As[kk][ty * 8 + 4];
            float4 bv0 = *(const float4*)&Bs[kk][tx * 8];
            float4 bv1 = *(const float4*)&Bs[kk][tx * 8 + 4];
            float a[8] = {av0.x, av0.y, av0.z, av0.w, av1.x, av1.y, av1.z, av1.w};
            float b[8] = {bv0.x, bv0.y, bv0.z, bv0.w, bv1.x, bv1.y, bv1.z, bv1.w};
#pragma unroll
            for (int i = 0; i < 8; ++i)
#pragma unroll
                for (int j = 0; j < 8; ++j)
                    acc[i][j] = fmaf(a[i], b[j], acc[i][j]);
        }
    }
#pragma unroll
    for (int i = 0; i < 8; ++i) {
        float* dst = z_pre + (size_t)(n0 + ty * 8 + i) * D_SAE + s0 + tx * 8;
        *(float4*)(dst)     = make_float4(acc[i][0], acc[i][1], acc[i][2], acc[i][3]);
        *(float4*)(dst + 4) = make_float4(acc[i][4], acc[i][5], acc[i][6], acc[i][7]);
    }
}

// ---------------------------------------------------------------------------
// Kernel 2: exact per-row top-K via radix select (unchanged, verified R1)
// ---------------------------------------------------------------------------
__global__ __launch_bounds__(256) void topk_select(
    const float* __restrict__ z_pre, float* __restrict__ z,
    int* __restrict__ out_idx, float* __restrict__ out_val)
{
    __shared__ unsigned int su[D_SAE];
    __shared__ unsigned int hist[256];
    __shared__ unsigned int sscan[256];
    __shared__ int s_bin; __shared__ unsigned int s_sub;
    __shared__ unsigned int eq_cnt, sel_cnt;
    __shared__ int eidx[64];
    __shared__ int s_need;
    __shared__ int cidx[KTOP];
    __shared__ float cval[KTOP];

    const int row = blockIdx.x;
    const int tid = threadIdx.x;
    const float* src = z_pre + (size_t)row * D_SAE;

    for (int i = tid; i < D_SAE; i += 256) {
        unsigned int b = __float_as_uint(src[i]);
        su[i] = (b & 0x80000000u) ? ~b : (b | 0x80000000u);
    }
    __syncthreads();

    unsigned int prefix = 0u, pmask = 0u;
    int need = KTOP;
    for (int level = 0; level < 4; ++level) {
        const int shift = 24 - 8 * level;
        hist[tid] = 0u;
        __syncthreads();
        for (int i = tid; i < D_SAE; i += 256) {
            unsigned int ui = su[i];
            if ((ui & pmask) == prefix)
                atomicAdd(&hist[(ui >> shift) & 0xffu], 1u);
        }
        __syncthreads();
        sscan[tid] = hist[tid];
        __syncthreads();
        for (int off = 1; off < 256; off <<= 1) {
            unsigned int v = (tid + off < 256) ? sscan[tid + off] : 0u;
            __syncthreads();
            sscan[tid] += v;
            __syncthreads();
        }
        {
            unsigned int ge = sscan[tid];
            unsigned int gt = (tid < 255) ? sscan[tid + 1] : 0u;
            if ((int)ge >= need && (int)gt < need) { s_bin = tid; s_sub = gt; }
        }
        __syncthreads();
        prefix |= ((unsigned int)s_bin) << shift;
        pmask  |= 0xffu << shift;
        need   -= (int)s_sub;
        __syncthreads();
    }
    const unsigned int T = prefix;

    if (tid == 0) { eq_cnt = 0u; sel_cnt = 0u; }
    __syncthreads();
    for (int i = tid; i < D_SAE; i += 256) {
        if (su[i] == T) {
            unsigned int p = atomicAdd(&eq_cnt, 1u);
            if (p < 64u) eidx[p] = i;
        }
    }
    __syncthreads();
    if (tid == 0) {
        int ec = (int)(eq_cnt < 64u ? eq_cnt : 64u);
        for (int a = 1; a < ec; ++a) {
            int v = eidx[a]; int b = a - 1;
            while (b >= 0 && eidx[b] > v) { eidx[b + 1] = eidx[b]; --b; }
            eidx[b + 1] = v;
        }
        s_need = need;
    }
    __syncthreads();
    const int neq = s_need;

    for (int i = tid; i < D_SAE; i += 256) {
        unsigned int ui = su[i];
        bool sel = (ui > T);
        if (!sel && ui == T) {
            for (int k = 0; k < neq; ++k)
                if (eidx[k] == i) { sel = true; break; }
        }
        unsigned int fb = (ui & 0x80000000u) ? (ui & 0x7fffffffu) : ~ui;
        float fv = __uint_as_float(fb);
        z[(size_t)row * D_SAE + i] = sel ? fv : 0.0f;
        if (sel) {
            unsigned int p = atomicAdd(&sel_cnt, 1u);
            if (p < (unsigned)KTOP) { cidx[p] = i; cval[p] = fv; }
        }
    }
    __syncthreads();
    if (out_idx != nullptr) {
        if (tid == 0) {
            int m = (int)(sel_cnt < (unsigned)KTOP ? sel_cnt : (unsigned)KTOP);
            for (int a = 1; a < m; ++a) {
                int vi = cidx[a]; float vv = cval[a]; int b = a - 1;
                while (b >= 0 && cidx[b] > vi) {
                    cidx[b + 1] = cidx[b]; cval[b + 1] = cval[b]; --b;
                }
                cidx[b + 1] = vi; cval[b + 1] = vv;
            }
            for (int a = m; a < KTOP; ++a) { cidx[a] = 0; cval[a] = 0.0f; }
        }
        __syncthreads();
        if (tid < KTOP) {
            out_idx[row * KTOP + tid] = cidx[tid];
            out_val[row * KTOP + tid] = cval[tid];
        }
    }
}

// ---------------------------------------------------------------------------
// Kernel 3: W_dec transpose (unchanged)
// ---------------------------------------------------------------------------
__global__ __launch_bounds__(256) void transpose_wdec(
    const float* __restrict__ in, float* __restrict__ out)
{
    __shared__ float tile[32][33];
    const int tid = threadIdx.x;
    const int lx = tid & 31, ly = tid >> 5;
    const int j0 = blockIdx.x * 32;
    const int d0 = blockIdx.y * 32;
#pragma unroll
    for (int r = 0; r < 4; ++r) {
        int d = d0 + ly + r * 8;
        tile[ly + r * 8][lx] = in[(size_t)d * D_SAE + j0 + lx];
    }
    __syncthreads();
#pragma unroll
    for (int r = 0; r < 4; ++r) {
        int j = j0 + ly + r * 8;
        out[(size_t)j * D_IN + d0 + lx] = tile[lx][ly + r * 8];
    }
}

// ---------------------------------------------------------------------------
// Kernel 4a: sparse decode from (idx,val) lists (unchanged)
// ---------------------------------------------------------------------------
__global__ __launch_bounds__(256) void decode_fast(
    const float* __restrict__ WdT, const int* __restrict__ idx,
    const float* __restrict__ val, const float* __restrict__ b_pre,
    const float* __restrict__ b_dec, float* __restrict__ x_hat)
{
    __shared__ int   sj[KTOP];
    __shared__ float sv[KTOP];
    const int row = blockIdx.x, tid = threadIdx.x;
    if (tid < KTOP) { sj[tid] = idx[row * KTOP + tid]; sv[tid] = val[row * KTOP + tid]; }
    __syncthreads();
    const int d = tid * 4;
    float4 bd = *(const float4*)(b_dec + d);
    float4 bp = *(const float4*)(b_pre + d);
    float4 acc = make_float4(bd.x + bp.x, bd.y + bp.y, bd.z + bp.z, bd.w + bp.w);
#pragma unroll
    for (int j = 0; j < KTOP; ++j) {
        const float v = sv[j];
        const float4 w = *(const float4*)(WdT + (size_t)sj[j] * D_IN + d);
        acc.x = fmaf(v, w.x, acc.x); acc.y = fmaf(v, w.y, acc.y);
        acc.z = fmaf(v, w.z, acc.z); acc.w = fmaf(v, w.w, acc.w);
    }
    *(float4*)(x_hat + (size_t)row * D_IN + d) = acc;
}

// ---------------------------------------------------------------------------
// Kernel 4b: fallback decode (unchanged)
// ---------------------------------------------------------------------------
__global__ __launch_bounds__(256) void decode_slow(
    const float* __restrict__ W_dec, const float* __restrict__ z,
    const float* __restrict__ b_pre, const float* __restrict__ b_dec,
    float* __restrict__ x_hat)
{
    __shared__ int   sj[64];
    __shared__ float sv[64];
    __shared__ unsigned int cnt;
    __shared__ int s_m;
    const int row = blockIdx.x, tid = threadIdx.x;
    if (tid == 0) cnt = 0u;
    __syncthreads();
    const float* zr = z + (size_t)row * D_SAE;
    for (int i = tid; i < D_SAE; i += 256) {
        float v = zr[i];
        if (v != 0.0f) { unsigned p = atomicAdd(&cnt, 1u); if (p < 64u) { sj[p] = i; sv[p] = v; } }
    }
    __syncthreads();
    if (tid == 0) {
        int m = (int)(cnt < 64u ? cnt : 64u);
        for (int a = 1; a < m; ++a) {
            int vi = sj[a]; float vv = sv[a]; int b = a - 1;
            while (b >= 0 && sj[b] > vi) { sj[b + 1] = sj[b]; sv[b + 1] = sv[b]; --b; }
            sj[b + 1] = vi; sv[b + 1] = vv;
        }
        s_m = m;
    }
    __syncthreads();
    const int m = s_m;
    const int d = tid * 4;
    float4 bd = *(const float4*)(b_dec + d);
    float4 bp = *(const float4*)(b_pre + d);
    float4 acc = make_float4(bd.x + bp.x, bd.y + bp.y, bd.z + bp.z, bd.w + bp.w);
    for (int j = 0; j < m; ++j) {
        float v = sv[j];
        size_t c = (size_t)sj[j];
        acc.x = fmaf(v, W_dec[(size_t)(d + 0) * D_SAE + c], acc.x);
        acc.y = fmaf(v, W_dec[(size_t)(d + 1) * D_SAE + c], acc.y);
        acc.z = fmaf(v, W_dec[(size_t)(d + 2) * D_SAE + c], acc.z);
        acc.w = fmaf(v, W_dec[(size_t)(d + 3) * D_SAE + c], acc.w);
    }
    *(float4*)(x_hat + (size_t)row * D_IN + d) = acc;
}

// ---------------------------------------------------------------------------
extern "C" void kernel_launch(void* const* d_in, const int* in_sizes, int n_in,
                              void* d_out, int out_size, void* d_ws, size_t ws_size,
                              hipStream_t stream)
{
    const float* x     = (const float*)d_in[0];
    const float* b_pre = (const float*)d_in[1];
    const float* W_enc = (const float*)d_in[2];
    const float* W_dec = (const float*)d_in[3];
    const float* b_dec = (const float*)d_in[4];

    float* x_hat = (float*)d_out;
    float* z     = x_hat + (size_t)NROWS * D_IN;
    float* z_pre = z + (size_t)NROWS * D_SAE;

    const size_t wdt_bytes  = (size_t)D_SAE * D_IN * sizeof(float);
    const size_t list_bytes = (size_t)NROWS * KTOP * (sizeof(int) + sizeof(float));
    const size_t a2_bytes   = (size_t)NROWS * KSPLIT * sizeof(_Float16);
    const size_t b2_bytes   = (size_t)D_SAE * KSPLIT * sizeof(_Float16);

    char* p = (char*)d_ws;
    float*    WdT  = (float*)p;            p += wdt_bytes;
    int*      idxl = (int*)p;              p += (size_t)NROWS * KTOP * sizeof(int);
    float*    vall = (float*)p;            p += (size_t)NROWS * KTOP * sizeof(float);
    _Float16* A2   = (_Float16*)p;         p += a2_bytes;
    _Float16* B2   = (_Float16*)p;

    const bool fast = (ws_size >= wdt_bytes + list_bytes);
    const bool mfma = (ws_size >= wdt_bytes + list_bytes + a2_bytes + b2_bytes);

    if (mfma) {
        split_x<<<NROWS, 256, 0, stream>>>(x, b_pre, A2);
        split_w<<<D_SAE, 256, 0, stream>>>(W_enc, B2);
        encode_mfma<<<dim3(D_SAE / 128, NROWS / 128), 256, 0, stream>>>(A2, B2, z_pre);
    } else {
        encode_gemm<<<dim3(D_SAE / 128, NROWS / 128), 256, 0, stream>>>(x, b_pre, W_enc, z_pre);
    }

    if (fast) {
        transpose_wdec<<<dim3(D_SAE / 32, D_IN / 32), 256, 0, stream>>>(W_dec, WdT);
        topk_select<<<NROWS, 256, 0, stream>>>(z_pre, z, idxl, vall);
        decode_fast<<<NROWS, 256, 0, stream>>>(WdT, idxl, vall, b_pre, b_dec, x_hat);
    } else {
        topk_select<<<NROWS, 256, 0, stream>>>(z_pre, z, nullptr, nullptr);
        decode_slow<<<NROWS, 256, 0, stream>>>(W_dec, z, b_pre, b_dec, x_hat);
    }
}

// Round 4
// 1510.663 us; speedup vs baseline: 2.7946x; 1.3226x over previous
//
#include <hip/hip_runtime.h>

#define D_IN   1024
#define D_SAE  16384
#define KTOP   32
#define NROWS  8192
#define KSPLIT 3072   // A: [lo*2048 | hi | hi],  B: [hi | lo*2048 | hi]
#define LOSCALE 2048.0f
#define INV_LOSCALE 4.8828125e-4f   // 2^-11, exact
#define CAND_CAP 512

typedef _Float16 f16x8 __attribute__((ext_vector_type(8)));
typedef float    f32x4 __attribute__((ext_vector_type(4)));

// ---------------------------------------------------------------------------
// Split kernels (unchanged from R3, verified): fp32 -> (hi, lo*2048) fp16.
// ---------------------------------------------------------------------------
__global__ __launch_bounds__(256) void split_x(
    const float* __restrict__ x, const float* __restrict__ b_pre,
    _Float16* __restrict__ A2)
{
    const int n   = blockIdx.x;
    const int tid = threadIdx.x;
    const int k   = tid * 4;
    float4 v  = *(const float4*)(x + (size_t)n * D_IN + k);
    float4 bp = *(const float4*)(b_pre + k);
    v.x -= bp.x; v.y -= bp.y; v.z -= bp.z; v.w -= bp.w;
    _Float16 h[4], l[4];
    h[0] = (_Float16)v.x; l[0] = (_Float16)((v.x - (float)h[0]) * LOSCALE);
    h[1] = (_Float16)v.y; l[1] = (_Float16)((v.y - (float)h[1]) * LOSCALE);
    h[2] = (_Float16)v.z; l[2] = (_Float16)((v.z - (float)h[2]) * LOSCALE);
    h[3] = (_Float16)v.w; l[3] = (_Float16)((v.w - (float)h[3]) * LOSCALE);
    _Float16* row = A2 + (size_t)n * KSPLIT;
    *(ulong1*)(row + k)        = *(ulong1*)l;
    *(ulong1*)(row + 1024 + k) = *(ulong1*)h;
    *(ulong1*)(row + 2048 + k) = *(ulong1*)h;
}

__global__ __launch_bounds__(256) void split_w(
    const float* __restrict__ W_enc, _Float16* __restrict__ B2)
{
    const int s   = blockIdx.x;
    const int tid = threadIdx.x;
    const int k   = tid * 4;
    float4 v = *(const float4*)(W_enc + (size_t)s * D_IN + k);
    _Float16 h[4], l[4];
    h[0] = (_Float16)v.x; l[0] = (_Float16)((v.x - (float)h[0]) * LOSCALE);
    h[1] = (_Float16)v.y; l[1] = (_Float16)((v.y - (float)h[1]) * LOSCALE);
    h[2] = (_Float16)v.z; l[2] = (_Float16)((v.z - (float)h[2]) * LOSCALE);
    h[3] = (_Float16)v.w; l[3] = (_Float16)((v.w - (float)h[3]) * LOSCALE);
    _Float16* row = B2 + (size_t)s * KSPLIT;
    *(ulong1*)(row + k)        = *(ulong1*)h;
    *(ulong1*)(row + 1024 + k) = *(ulong1*)l;
    *(ulong1*)(row + 2048 + k) = *(ulong1*)h;
}

// ---------------------------------------------------------------------------
// Kernel 1: encode MFMA GEMM, K=3072, rescale at k=2048 (unchanged from R3).
// ---------------------------------------------------------------------------
__device__ __forceinline__ void gload_lds16(const void* g, void* lds) {
    __builtin_amdgcn_global_load_lds(
        (const __attribute__((address_space(1))) unsigned int*)g,
        (__attribute__((address_space(3))) unsigned int*)lds, 16, 0, 0);
}

__global__ __launch_bounds__(256, 2) void encode_mfma(
    const _Float16* __restrict__ A2, const _Float16* __restrict__ B2,
    float* __restrict__ z_pre)
{
    __shared__ _Float16 Asl[128 * 64];
    __shared__ _Float16 Bsl[128 * 64];

    const int tid  = threadIdx.x;
    const int wid  = tid >> 6;
    const int lane = tid & 63;
    const int wr   = wid >> 1;
    const int wc   = wid & 1;
    const int brow = blockIdx.y * 128;
    const int bcol = blockIdx.x * 128;

    const int srow = (lane >> 3);
    const int scol = (lane & 7) * 8;

    const int fr = lane & 15;
    const int fk = (lane >> 4) * 8;

    f32x4 acc[4][4] = {};

    for (int k0 = 0; k0 < KSPLIT; k0 += 64) {
        if (k0 == 2048) {
#pragma unroll
            for (int m = 0; m < 4; ++m)
#pragma unroll
                for (int n = 0; n < 4; ++n) {
                    acc[m][n][0] *= INV_LOSCALE;
                    acc[m][n][1] *= INV_LOSCALE;
                    acc[m][n][2] *= INV_LOSCALE;
                    acc[m][n][3] *= INV_LOSCALE;
                }
        }
#pragma unroll
        for (int t = 0; t < 4; ++t) {
            const int rg = (wid * 4 + t) * 8 + srow;
            const char* ldsA = (const char*)Asl + (wid * 4 + t) * 1024;
            const char* ldsB = (const char*)Bsl + (wid * 4 + t) * 1024;
            gload_lds16(A2 + (size_t)(brow + rg) * KSPLIT + k0 + scol, (void*)ldsA);
            gload_lds16(B2 + (size_t)(bcol + rg) * KSPLIT + k0 + scol, (void*)ldsB);
        }
        __syncthreads();

#pragma unroll
        for (int kk = 0; kk < 2; ++kk) {
            f16x8 a[4], b[4];
#pragma unroll
            for (int m = 0; m < 4; ++m)
                a[m] = *(const f16x8*)&Asl[(wr * 64 + m * 16 + fr) * 64 + kk * 32 + fk];
#pragma unroll
            for (int n = 0; n < 4; ++n)
                b[n] = *(const f16x8*)&Bsl[(wc * 64 + n * 16 + fr) * 64 + kk * 32 + fk];
#pragma unroll
            for (int m = 0; m < 4; ++m)
#pragma unroll
                for (int n = 0; n < 4; ++n)
                    acc[m][n] = __builtin_amdgcn_mfma_f32_16x16x32_f16(a[m], b[n], acc[m][n], 0, 0, 0);
        }
        __syncthreads();
    }

#pragma unroll
    for (int m = 0; m < 4; ++m) {
        const int r0 = brow + wr * 64 + m * 16 + (lane >> 4) * 4;
#pragma unroll
        for (int n = 0; n < 4; ++n) {
            float* dst = z_pre + (size_t)r0 * D_SAE + bcol + wc * 64 + n * 16 + (lane & 15);
#pragma unroll
            for (int j = 0; j < 4; ++j)
                dst[(size_t)j * D_SAE] = acc[m][n][j];
        }
    }
}

// ---------------------------------------------------------------------------
// Kernel 1 (fallback): fp32 vector GEMM (unchanged)
// ---------------------------------------------------------------------------
__global__ __launch_bounds__(256, 2) void encode_gemm(
    const float* __restrict__ x, const float* __restrict__ b_pre,
    const float* __restrict__ W_enc, float* __restrict__ z_pre)
{
    __shared__ float As[16][132];
    __shared__ float Bs[16][132];
    const int tid = threadIdx.x;
    const int n0  = blockIdx.y * 128;
    const int s0  = blockIdx.x * 128;
    const int ty  = tid >> 4;
    const int tx  = tid & 15;
    const int r0  = tid >> 2;
    const int r1  = r0 + 64;
    const int kq  = (tid & 3) * 4;
    float acc[8][8];
#pragma unroll
    for (int i = 0; i < 8; ++i)
#pragma unroll
        for (int j = 0; j < 8; ++j) acc[i][j] = 0.0f;
    const float* xA = x     + (size_t)n0 * D_IN;
    const float* wB = W_enc + (size_t)s0 * D_IN;
    for (int k0 = 0; k0 < D_IN; k0 += 16) {
        float4 a0 = *(const float4*)(xA + (size_t)r0 * D_IN + k0 + kq);
        float4 a1 = *(const float4*)(xA + (size_t)r1 * D_IN + k0 + kq);
        float4 b0 = *(const float4*)(wB + (size_t)r0 * D_IN + k0 + kq);
        float4 b1 = *(const float4*)(wB + (size_t)r1 * D_IN + k0 + kq);
        float4 bp = *(const float4*)(b_pre + k0 + kq);
        a0.x -= bp.x; a0.y -= bp.y; a0.z -= bp.z; a0.w -= bp.w;
        a1.x -= bp.x; a1.y -= bp.y; a1.z -= bp.z; a1.w -= bp.w;
        __syncthreads();
        As[kq + 0][r0] = a0.x; As[kq + 1][r0] = a0.y; As[kq + 2][r0] = a0.z; As[kq + 3][r0] = a0.w;
        As[kq + 0][r1] = a1.x; As[kq + 1][r1] = a1.y; As[kq + 2][r1] = a1.z; As[kq + 3][r1] = a1.w;
        Bs[kq + 0][r0] = b0.x; Bs[kq + 1][r0] = b0.y; Bs[kq + 2][r0] = b0.z; Bs[kq + 3][r0] = b0.w;
        Bs[kq + 0][r1] = b1.x; Bs[kq + 1][r1] = b1.y; Bs[kq + 2][r1] = b1.z; Bs[kq + 3][r1] = b1.w;
        __syncthreads();
#pragma unroll
        for (int kk = 0; kk < 16; ++kk) {
            float4 av0 = *(const float4*)&As[kk][ty * 8];
            float4 av1 = *(const float4*)&As[kk][ty * 8 + 4];
            float4 bv0 = *(const float4*)&Bs[kk][tx * 8];
            float4 bv1 = *(const float4*)&Bs[kk][tx * 8 + 4];
            float a[8] = {av0.x, av0.y, av0.z, av0.w, av1.x, av1.y, av1.z, av1.w};
            float b[8] = {bv0.x, bv0.y, bv0.z, bv0.w, bv1.x, bv1.y, bv1.z, bv1.w};
#pragma unroll
            for (int i = 0; i < 8; ++i)
#pragma unroll
                for (int j = 0; j < 8; ++j)
                    acc[i][j] = fmaf(a[i], b[j], acc[i][j]);
        }
    }
#pragma unroll
    for (int i = 0; i < 8; ++i) {
        float* dst = z_pre + (size_t)(n0 + ty * 8 + i) * D_SAE + s0 + tx * 8;
        *(float4*)(dst)     = make_float4(acc[i][0], acc[i][1], acc[i][2], acc[i][3]);
        *(float4*)(dst + 4) = make_float4(acc[i][4], acc[i][5], acc[i][6], acc[i][7]);
    }
}

// ---------------------------------------------------------------------------
// Kernel 2 (v2): per-row top-K, early-exit 12-bit radix select.
// No row staging (L2-resident re-reads). Level 0: hist of top 12 bits; if the
// boundary bin holds <= CAND_CAP elements (always, for non-degenerate data),
// collect and resolve exact ranks by (su, idx). Levels 1/2 + ballot tie-path
// are exactness fallbacks. Ties -> lowest index (lax.top_k semantics).
// ---------------------------------------------------------------------------
__device__ __forceinline__ unsigned int f2su(float f) {
    unsigned int b = __float_as_uint(f);
    return (b & 0x80000000u) ? ~b : (b | 0x80000000u);
}

__global__ __launch_bounds__(256) void topk_select2(
    const float* __restrict__ z_pre, float* __restrict__ z,
    int* __restrict__ out_idx, float* __restrict__ out_val)
{
    __shared__ unsigned int hist[4096];
    __shared__ unsigned int sb[256];
    __shared__ unsigned int cand_su[CAND_CAP];
    __shared__ int          cand_idx[CAND_CAP];
    __shared__ unsigned int cand_cnt;
    __shared__ int sel_list[KTOP];
    __shared__ int s_bin, s_gt;
    __shared__ int cidx[KTOP];
    __shared__ float cvals[KTOP];
    __shared__ unsigned int outcnt;
    __shared__ unsigned int wc[4];

    const int row  = blockIdx.x;
    const int tid  = threadIdx.x;
    const int wid  = tid >> 6;
    const int lane = tid & 63;
    const float* src = z_pre + (size_t)row * D_SAE;

    const int shifts[3] = {20, 8, 0};
    const int nbits_[3] = {12, 12, 8};

    unsigned int prefix = 0u, pmask = 0u;
    int need = KTOP;
    int mode = -1;          // 0 = candidate-resolve, 1 = all-ties fallback
    int shiftF = 0;

    for (int level = 0; level < 3; ++level) {
        const int shift = shifts[level];
        const unsigned int nb = 1u << nbits_[level];
        for (int i = tid; i < (int)nb; i += 256) hist[i] = 0u;
        __syncthreads();

        for (int it = 0; it < 16; ++it) {
            const int i4 = (it * 256 + tid) * 4;
            float4 v = *(const float4*)(src + i4);
#pragma unroll
            for (int e = 0; e < 4; ++e) {
                unsigned int su = f2su((&v.x)[e]);
                if ((su & pmask) == prefix)
                    atomicAdd(&hist[(su >> shift) & (nb - 1u)], 1u);
            }
        }
        __syncthreads();

        // suffix count: superbins of nb/256 bins per thread
        const int bpt = (int)(nb >> 8);
        unsigned int lsum = 0u;
        for (int j = 0; j < bpt; ++j) lsum += hist[tid * bpt + j];
        sb[tid] = lsum;
        __syncthreads();
        for (int off = 1; off < 256; off <<= 1) {
            unsigned int v = (tid + off < 256) ? sb[tid + off] : 0u;
            __syncthreads();
            sb[tid] += v;
            __syncthreads();
        }
        {
            unsigned int ge = sb[tid];
            unsigned int gt = (tid < 255) ? sb[tid + 1] : 0u;
            if ((int)ge >= need && (int)gt < need) {
                unsigned int run = gt;
                for (int j = bpt - 1; j >= 0; --j) {
                    unsigned int c = hist[tid * bpt + j];
                    if ((int)(run + c) >= need) { s_bin = tid * bpt + j; s_gt = (int)run; break; }
                    run += c;
                }
            }
        }
        __syncthreads();
        const int b  = s_bin;
        const int gt = s_gt;
        const int cntb = (int)hist[b];
        __syncthreads();           // everyone done reading hist before reuse

        need  -= gt;
        prefix |= ((unsigned int)b) << shift;
        pmask  |= (nb - 1u) << shift;

        if (cntb <= CAND_CAP) { mode = 0; shiftF = shift; break; }
        if (level == 2)       { mode = 1; shiftF = 0;     break; }
    }
    const unsigned int hb = prefix >> shiftF;

    if (mode == 0) {
        if (tid == 0) cand_cnt = 0u;
        __syncthreads();
        for (int it = 0; it < 16; ++it) {
            const int i4 = (it * 256 + tid) * 4;
            float4 v = *(const float4*)(src + i4);
#pragma unroll
            for (int e = 0; e < 4; ++e) {
                unsigned int su = f2su((&v.x)[e]);
                if ((su >> shiftF) == hb) {
                    unsigned int p = atomicAdd(&cand_cnt, 1u);
                    if (p < (unsigned)CAND_CAP) { cand_su[p] = su; cand_idx[p] = i4 + e; }
                }
            }
        }
        __syncthreads();
        const int cnt = (int)(cand_cnt < (unsigned)CAND_CAP ? cand_cnt : (unsigned)CAND_CAP);
        for (int c = tid; c < cnt; c += 256) {
            const unsigned int s = cand_su[c];
            const int id = cand_idx[c];
            int r = 0;
            for (int j = 0; j < cnt; ++j) {
                const unsigned int sj = cand_su[j];
                r += (sj > s) || (sj == s && cand_idx[j] < id);
            }
            if (r < need) sel_list[r] = id;
        }
        __syncthreads();
    } else {
        // all candidates share su == prefix exactly; pick `need` lowest indices
        int cum = 0;
        for (int seg = 0; seg < 64; ++seg) {
            const int i = seg * 256 + tid;
            const bool m = (f2su(src[i]) == prefix);
            const unsigned long long bm = __ballot(m);
            if (lane == 0) wc[wid] = (unsigned int)__popcll(bm);
            __syncthreads();
            int base = cum;
            for (int w = 0; w < wid; ++w) base += (int)wc[w];
            const int r = base + (int)__popcll(bm & ((1ull << lane) - 1ull));
            if (m && r < need) sel_list[r] = i;
            cum += (int)(wc[0] + wc[1] + wc[2] + wc[3]);
            __syncthreads();
            if (cum >= need) break;
        }
    }

    // write z + compact (idx,val)
    if (tid == 0) outcnt = 0u;
    __syncthreads();
    const int nsel = need;
    for (int it = 0; it < 16; ++it) {
        const int i4 = (it * 256 + tid) * 4;
        float4 v = *(const float4*)(src + i4);
        float o[4];
#pragma unroll
        for (int e = 0; e < 4; ++e) {
            const float f = (&v.x)[e];
            const unsigned int su = f2su(f);
            const unsigned int cls = su >> shiftF;
            bool sel = (cls > hb);
            if (!sel && cls == hb) {
                for (int k = 0; k < nsel; ++k)
                    if (sel_list[k] == i4 + e) { sel = true; break; }
            }
            o[e] = sel ? f : 0.0f;
            if (sel) {
                unsigned int p = atomicAdd(&outcnt, 1u);
                if (p < (unsigned)KTOP) { cidx[p] = i4 + e; cvals[p] = f; }
            }
        }
        *(float4*)(z + (size_t)row * D_SAE + i4) = make_float4(o[0], o[1], o[2], o[3]);
    }
    __syncthreads();
    if (out_idx != nullptr && tid < KTOP) {
        const int id = cidx[tid];
        const float vv = cvals[tid];
        int r = 0;
        for (int j = 0; j < KTOP; ++j) r += (cidx[j] < id);
        out_idx[row * KTOP + r] = id;
        out_val[row * KTOP + r] = vv;
    }
}

// ---------------------------------------------------------------------------
// Kernel 3: W_dec transpose (unchanged)
// ---------------------------------------------------------------------------
__global__ __launch_bounds__(256) void transpose_wdec(
    const float* __restrict__ in, float* __restrict__ out)
{
    __shared__ float tile[32][33];
    const int tid = threadIdx.x;
    const int lx = tid & 31, ly = tid >> 5;
    const int j0 = blockIdx.x * 32;
    const int d0 = blockIdx.y * 32;
#pragma unroll
    for (int r = 0; r < 4; ++r) {
        int d = d0 + ly + r * 8;
        tile[ly + r * 8][lx] = in[(size_t)d * D_SAE + j0 + lx];
    }
    __syncthreads();
#pragma unroll
    for (int r = 0; r < 4; ++r) {
        int j = j0 + ly + r * 8;
        out[(size_t)j * D_IN + d0 + lx] = tile[lx][ly + r * 8];
    }
}

// ---------------------------------------------------------------------------
// Kernel 4a: sparse decode from (idx,val) lists (unchanged)
// ---------------------------------------------------------------------------
__global__ __launch_bounds__(256) void decode_fast(
    const float* __restrict__ WdT, const int* __restrict__ idx,
    const float* __restrict__ val, const float* __restrict__ b_pre,
    const float* __restrict__ b_dec, float* __restrict__ x_hat)
{
    __shared__ int   sj[KTOP];
    __shared__ float sv[KTOP];
    const int row = blockIdx.x, tid = threadIdx.x;
    if (tid < KTOP) { sj[tid] = idx[row * KTOP + tid]; sv[tid] = val[row * KTOP + tid]; }
    __syncthreads();
    const int d = tid * 4;
    float4 bd = *(const float4*)(b_dec + d);
    float4 bp = *(const float4*)(b_pre + d);
    float4 acc = make_float4(bd.x + bp.x, bd.y + bp.y, bd.z + bp.z, bd.w + bp.w);
#pragma unroll
    for (int j = 0; j < KTOP; ++j) {
        const float v = sv[j];
        const float4 w = *(const float4*)(WdT + (size_t)sj[j] * D_IN + d);
        acc.x = fmaf(v, w.x, acc.x); acc.y = fmaf(v, w.y, acc.y);
        acc.z = fmaf(v, w.z, acc.z); acc.w = fmaf(v, w.w, acc.w);
    }
    *(float4*)(x_hat + (size_t)row * D_IN + d) = acc;
}

// ---------------------------------------------------------------------------
// Kernel 4b: fallback decode (unchanged)
// ---------------------------------------------------------------------------
__global__ __launch_bounds__(256) void decode_slow(
    const float* __restrict__ W_dec, const float* __restrict__ z,
    const float* __restrict__ b_pre, const float* __restrict__ b_dec,
    float* __restrict__ x_hat)
{
    __shared__ int   sj[64];
    __shared__ float sv[64];
    __shared__ unsigned int cnt;
    __shared__ int s_m;
    const int row = blockIdx.x, tid = threadIdx.x;
    if (tid == 0) cnt = 0u;
    __syncthreads();
    const float* zr = z + (size_t)row * D_SAE;
    for (int i = tid; i < D_SAE; i += 256) {
        float v = zr[i];
        if (v != 0.0f) { unsigned p = atomicAdd(&cnt, 1u); if (p < 64u) { sj[p] = i; sv[p] = v; } }
    }
    __syncthreads();
    if (tid == 0) {
        int m = (int)(cnt < 64u ? cnt : 64u);
        for (int a = 1; a < m; ++a) {
            int vi = sj[a]; float vv = sv[a]; int b = a - 1;
            while (b >= 0 && sj[b] > vi) { sj[b + 1] = sj[b]; sv[b + 1] = sv[b]; --b; }
            sj[b + 1] = vi; sv[b + 1] = vv;
        }
        s_m = m;
    }
    __syncthreads();
    const int m = s_m;
    const int d = tid * 4;
    float4 bd = *(const float4*)(b_dec + d);
    float4 bp = *(const float4*)(b_pre + d);
    float4 acc = make_float4(bd.x + bp.x, bd.y + bp.y, bd.z + bp.z, bd.w + bp.w);
    for (int j = 0; j < m; ++j) {
        float v = sv[j];
        size_t c = (size_t)sj[j];
        acc.x = fmaf(v, W_dec[(size_t)(d + 0) * D_SAE + c], acc.x);
        acc.y = fmaf(v, W_dec[(size_t)(d + 1) * D_SAE + c], acc.y);
        acc.z = fmaf(v, W_dec[(size_t)(d + 2) * D_SAE + c], acc.z);
        acc.w = fmaf(v, W_dec[(size_t)(d + 3) * D_SAE + c], acc.w);
    }
    *(float4*)(x_hat + (size_t)row * D_IN + d) = acc;
}

// ---------------------------------------------------------------------------
extern "C" void kernel_launch(void* const* d_in, const int* in_sizes, int n_in,
                              void* d_out, int out_size, void* d_ws, size_t ws_size,
                              hipStream_t stream)
{
    const float* x     = (const float*)d_in[0];
    const float* b_pre = (const float*)d_in[1];
    const float* W_enc = (const float*)d_in[2];
    const float* W_dec = (const float*)d_in[3];
    const float* b_dec = (const float*)d_in[4];

    float* x_hat = (float*)d_out;
    float* z     = x_hat + (size_t)NROWS * D_IN;
    float* z_pre = z + (size_t)NROWS * D_SAE;

    const size_t wdt_bytes  = (size_t)D_SAE * D_IN * sizeof(float);
    const size_t list_bytes = (size_t)NROWS * KTOP * (sizeof(int) + sizeof(float));
    const size_t a2_bytes   = (size_t)NROWS * KSPLIT * sizeof(_Float16);
    const size_t b2_bytes   = (size_t)D_SAE * KSPLIT * sizeof(_Float16);

    char* p = (char*)d_ws;
    float*    WdT  = (float*)p;            p += wdt_bytes;
    int*      idxl = (int*)p;              p += (size_t)NROWS * KTOP * sizeof(int);
    float*    vall = (float*)p;            p += (size_t)NROWS * KTOP * sizeof(float);
    _Float16* A2   = (_Float16*)p;         p += a2_bytes;
    _Float16* B2   = (_Float16*)p;

    const bool fast = (ws_size >= wdt_bytes + list_bytes);
    const bool mfma = (ws_size >= wdt_bytes + list_bytes + a2_bytes + b2_bytes);

    if (mfma) {
        split_x<<<NROWS, 256, 0, stream>>>(x, b_pre, A2);
        split_w<<<D_SAE, 256, 0, stream>>>(W_enc, B2);
        encode_mfma<<<dim3(D_SAE / 128, NROWS / 128), 256, 0, stream>>>(A2, B2, z_pre);
    } else {
        encode_gemm<<<dim3(D_SAE / 128, NROWS / 128), 256, 0, stream>>>(x, b_pre, W_enc, z_pre);
    }

    if (fast) {
        transpose_wdec<<<dim3(D_SAE / 32, D_IN / 32), 256, 0, stream>>>(W_dec, WdT);
        topk_select2<<<NROWS, 256, 0, stream>>>(z_pre, z, idxl, vall);
        decode_fast<<<NROWS, 256, 0, stream>>>(WdT, idxl, vall, b_pre, b_dec, x_hat);
    } else {
        topk_select2<<<NROWS, 256, 0, stream>>>(z_pre, z, nullptr, nullptr);
        decode_slow<<<NROWS, 256, 0, stream>>>(W_dec, z, b_pre, b_dec, x_hat);
    }
}